// Round 2
// baseline (2209.509 us; speedup 1.0000x reference)
//
#include <hip/hip_runtime.h>
#include <math.h>
#include <stdint.h>

#define T_ 512
#define B_ 64
#define I_ 512
#define H_ 512
#define G_ 2048   // 4*H
#define K_ 1024   // I + H
#define NMR 32    // unit-group WGs (each owns 16 hidden units)
#define NCOL 4    // batch-column WGs (each owns 16 batches)
#define NBLK (NMR * NCOL)   // 128 persistent workgroups, 1 per CU

typedef __bf16 bf16x8 __attribute__((ext_vector_type(8)));
typedef float f32x4 __attribute__((ext_vector_type(4)));
typedef int i32x4 __attribute__((ext_vector_type(4)));

// Workspace layout (bytes):
//   W bf16 [G_][K_]     : 4 MB    ([W_ih | W_hh], bf16)
//   bias f32 [G_]       : 8 KB
//   hswz bf16 [2][64KB] : 128 KB  (h in MFMA B-frag layout, double-buffered)
//   flags u32 [4][128]  : 2 KB    (per-column, per-WAVE progress flags)
//   xswz bf16 [T][64KB] : 32 MB   (x in MFMA B-frag layout, read cached)
#define OFF_W    ((size_t)0)
#define OFF_BIAS (OFF_W + (size_t)G_ * K_ * 2)
#define OFF_HSWZ (OFF_BIAS + (size_t)G_ * 4)
#define OFF_BAR  (OFF_HSWZ + (size_t)2 * H_ * B_ * 2)
#define OFF_XSWZ (OFF_BAR + 2048)

// B-frag swizzle: frag-slot s = (kblk*4 + nblk)*64 + lane, holding 8 bf16:
//   quad = lane>>4, l16 = lane&15;  b = nblk*16 + l16;  k = kblk*32 + quad*8 + j

__global__ void prep_w(const float* __restrict__ W_ih, const float* __restrict__ W_hh,
                       const float* __restrict__ b_ih, const float* __restrict__ b_hh,
                       char* __restrict__ ws) {
    __bf16* W = (__bf16*)(ws + OFF_W);
    float* bias = (float*)(ws + OFF_BIAS);
    int idx = blockIdx.x * 256 + threadIdx.x;   // over G_*K_ = 2M
    int g = idx >> 10;
    int k = idx & (K_ - 1);
    float v = (k < I_) ? W_ih[g * I_ + k] : W_hh[g * H_ + (k - I_)];
    W[idx] = (__bf16)v;
    if (idx < G_) bias[idx] = b_ih[idx] + b_hh[idx];
    if (idx < 512) ((unsigned*)(ws + OFF_BAR))[idx] = 0u;
}

__global__ void prep_x(const float* __restrict__ input, char* __restrict__ ws) {
    __bf16* xswz = (__bf16*)(ws + OFF_XSWZ);
    int s = blockIdx.x * 256 + threadIdx.x;   // frag-chunk id
    int lane = s & 63;
    int nblk = (s >> 6) & 3;
    int kblk = (s >> 8) & 15;
    int t = s >> 12;
    int b = nblk * 16 + (lane & 15);
    int k = kblk * 32 + (lane >> 4) * 8;
    const float* src = input + ((size_t)t * B_ + b) * I_ + k;
    float4 v0 = *(const float4*)src;
    float4 v1 = *(const float4*)(src + 4);
    bf16x8 o;
    o[0]=(__bf16)v0.x; o[1]=(__bf16)v0.y; o[2]=(__bf16)v0.z; o[3]=(__bf16)v0.w;
    o[4]=(__bf16)v1.x; o[5]=(__bf16)v1.y; o[6]=(__bf16)v1.z; o[7]=(__bf16)v1.w;
    *(bf16x8*)(xswz + (size_t)s * 8) = o;
}

__global__ void prep_h0(const float* __restrict__ h0, char* __restrict__ ws) {
    __bf16* hswz0 = (__bf16*)(ws + OFF_HSWZ);   // parity 0: read by step t=511
    int s = blockIdx.x * 256 + threadIdx.x;     // 4096 slots
    int lane = s & 63;
    int nblk = (s >> 6) & 3;
    int hk = s >> 8;
    int b = nblk * 16 + (lane & 15);
    int u = hk * 32 + (lane >> 4) * 8;
    const float* src = h0 + (size_t)b * H_ + u;
    float4 v0 = *(const float4*)src;
    float4 v1 = *(const float4*)(src + 4);
    bf16x8 o;
    o[0]=(__bf16)v0.x; o[1]=(__bf16)v0.y; o[2]=(__bf16)v0.z; o[3]=(__bf16)v0.w;
    o[4]=(__bf16)v1.x; o[5]=(__bf16)v1.y; o[6]=(__bf16)v1.z; o[7]=(__bf16)v1.w;
    *(bf16x8*)(hswz0 + (size_t)s * 8) = o;
}

__device__ __forceinline__ float sigmoid_f(float x) { return 1.f / (1.f + __expf(-x)); }
__device__ __forceinline__ float tanh_f(float x) { return 1.f - 2.f / (1.f + __expf(2.f * x)); }

// Persistent reverse scan, 128 WGs x 256 threads (1/CU). WG (m,n) owns hidden
// units [m*16,m*16+16) x batches [n*16,n*16+16); wave = gate type (M=16 rows,
// N=16, K=1024 -> 32 MFMAs/wave/step), 4 accumulators (dep chains of 8).
// h frags staged into WAVE-PRIVATE LDS via global_load_lds (sc0sc1), counted
// vmcnt(12/8/4/0) waits -> no cross-wave h rendezvous, no in-flight-register
// hazard (all consumers are ds_reads ordered by "memory"-clobber asm).
// Per-WAVE publish + per-wave flags (128/column); release = publish ->
// vmcnt(0) -> flag (no other vmem in between). gl exchange parity-buffered:
// per step 1 raw s_barrier + 1 __syncthreads (both drain-free).
__launch_bounds__(256, 1)
__global__ void lstm_persist(const float* __restrict__ c0, float* out,
                             char* __restrict__ ws) {
    __shared__ __attribute__((aligned(16))) __bf16 xbuf[8192];      // 16 KB
    __shared__ __attribute__((aligned(16))) __bf16 hbuf[4][8192];   // 64 KB, per-wave
    __shared__ float gl[2][4][16][17];                              // parity-buffered
    __shared__ __attribute__((aligned(16))) __bf16 hsc[4][64];      // per-wave gather

    const __bf16* W = (const __bf16*)(ws + OFF_W);
    const float* bias = (const float*)(ws + OFF_BIAS);
    __bf16* Hswz = (__bf16*)(ws + OFF_HSWZ);    // [2][32768 elements]
    const __bf16* Xswz = (const __bf16*)(ws + OFF_XSWZ);
    unsigned* flags = (unsigned*)(ws + OFF_BAR);

    const int tid = threadIdx.x;
    const int wave = tid >> 6;      // gate type
    const int lane = tid & 63;
    const int l16 = lane & 15;
    const int quad = lane >> 4;
    const int wgM = blockIdx.x & 31;    // unit group
    const int wgN = blockIdx.x >> 5;    // batch column

    // ---- A-fragments resident: ks 0..15 = W_ih cols, 16..31 = W_hh (128 VGPRs)
    bf16x8 A[32];
    {
        const size_t arow = (size_t)(wave * H_ + wgM * 16 + l16) * K_ + quad * 8;
        #pragma unroll
        for (int ks = 0; ks < 32; ++ks)
            A[ks] = *(const bf16x8*)(W + arow + ks * 32);
    }

    // ---- cell state: thread owns (unit u = tid&15, batch bl = tid>>4)
    const int cu_u = tid & 15;
    const int cu_bl = tid >> 4;
    const int hu = wgM * 16 + cu_u;
    const int batch = wgN * 16 + cu_bl;
    float creg = c0[(size_t)batch * H_ + hu];
    const float bias_i = bias[hu];
    const float bias_f = bias[H_ + hu];
    const float bias_g = bias[2 * H_ + hu];
    const float bias_o = bias[3 * H_ + hu];

    #define ISSUE_X(tt) do {                                                          \
        const __bf16* xb_ = Xswz + (size_t)(tt) * 32768;                              \
        _Pragma("unroll")                                                             \
        for (int i_ = 0; i_ < 4; ++i_) {                                              \
            const int kb_ = wave * 4 + i_;                                            \
            __builtin_amdgcn_global_load_lds(                                         \
                (const __attribute__((address_space(1))) void*)(xb_ + (size_t)((kb_ * 4 + wgN) * 64 + lane) * 8), \
                (__attribute__((address_space(3))) void*)(xbuf + kb_ * 512),          \
                16, 0, 0);                                                            \
        }                                                                             \
    } while (0)

    // Wave-private h staging: all 16 frags for nblk=wgN into hbuf[wave].
    #define ISSUE_H(par) do {                                                         \
        const __bf16* hb_ = Hswz + (size_t)(par) * 32768;                             \
        _Pragma("unroll")                                                             \
        for (int f_ = 0; f_ < 16; ++f_) {                                             \
            __builtin_amdgcn_global_load_lds(                                         \
                (const __attribute__((address_space(1))) void*)(hb_ + (size_t)((f_ * 4 + wgN) * 64 + lane) * 8), \
                (__attribute__((address_space(3))) void*)(hbuf[wave] + f_ * 512),     \
                16, 0, 0x11);                                                         \
        }                                                                             \
    } while (0)

    // ---- prologue: x-DMA + h-DMA for t=511 (h0 slab, parity 0)
    ISSUE_X(T_ - 1);
    ISSUE_H(0);
    asm volatile("s_waitcnt vmcnt(16)" ::: "memory");   // own x landed; h flying
    __builtin_amdgcn_sched_barrier(0);

    for (int t = T_ - 1; ; --t) {
        // ---- loop-top rendezvous: xbuf complete (each wave drained its own
        // x-DMA before arriving). RAW barrier: the 16 h-DMAs stay in flight.
        __builtin_amdgcn_s_barrier();
        __builtin_amdgcn_sched_barrier(0);

        // ---- x-phase: 16 MFMAs from xbuf, 4 accumulators (overlaps h-DMA RT)
        f32x4 ac0 = {0,0,0,0}, ac1 = {0,0,0,0}, ac2 = {0,0,0,0}, ac3 = {0,0,0,0};
        #pragma unroll
        for (int f = 0; f < 4; ++f) {
            bf16x8 b0 = *(const bf16x8*)(xbuf + (4*f+0) * 512 + lane * 8);
            bf16x8 b1 = *(const bf16x8*)(xbuf + (4*f+1) * 512 + lane * 8);
            bf16x8 b2 = *(const bf16x8*)(xbuf + (4*f+2) * 512 + lane * 8);
            bf16x8 b3 = *(const bf16x8*)(xbuf + (4*f+3) * 512 + lane * 8);
            ac0 = __builtin_amdgcn_mfma_f32_16x16x32_bf16(A[4*f+0], b0, ac0, 0, 0, 0);
            ac1 = __builtin_amdgcn_mfma_f32_16x16x32_bf16(A[4*f+1], b1, ac1, 0, 0, 0);
            ac2 = __builtin_amdgcn_mfma_f32_16x16x32_bf16(A[4*f+2], b2, ac2, 0, 0, 0);
            ac3 = __builtin_amdgcn_mfma_f32_16x16x32_bf16(A[4*f+3], b3, ac3, 0, 0, 0);
        }

        // ---- h-phase: counted vmcnt on own 16 h-DMAs, group of 4 at a time.
        // "memory" clobber keeps each group's ds_reads after its wait.
        const __bf16* hwb = hbuf[wave];
        asm volatile("s_waitcnt vmcnt(12)" ::: "memory");
        {
            bf16x8 b0 = *(const bf16x8*)(hwb + 0*512 + lane*8);
            bf16x8 b1 = *(const bf16x8*)(hwb + 1*512 + lane*8);
            bf16x8 b2 = *(const bf16x8*)(hwb + 2*512 + lane*8);
            bf16x8 b3 = *(const bf16x8*)(hwb + 3*512 + lane*8);
            ac0 = __builtin_amdgcn_mfma_f32_16x16x32_bf16(A[16], b0, ac0, 0, 0, 0);
            ac1 = __builtin_amdgcn_mfma_f32_16x16x32_bf16(A[17], b1, ac1, 0, 0, 0);
            ac2 = __builtin_amdgcn_mfma_f32_16x16x32_bf16(A[18], b2, ac2, 0, 0, 0);
            ac3 = __builtin_amdgcn_mfma_f32_16x16x32_bf16(A[19], b3, ac3, 0, 0, 0);
        }
        asm volatile("s_waitcnt vmcnt(8)" ::: "memory");
        {
            bf16x8 b0 = *(const bf16x8*)(hwb + 4*512 + lane*8);
            bf16x8 b1 = *(const bf16x8*)(hwb + 5*512 + lane*8);
            bf16x8 b2 = *(const bf16x8*)(hwb + 6*512 + lane*8);
            bf16x8 b3 = *(const bf16x8*)(hwb + 7*512 + lane*8);
            ac0 = __builtin_amdgcn_mfma_f32_16x16x32_bf16(A[20], b0, ac0, 0, 0, 0);
            ac1 = __builtin_amdgcn_mfma_f32_16x16x32_bf16(A[21], b1, ac1, 0, 0, 0);
            ac2 = __builtin_amdgcn_mfma_f32_16x16x32_bf16(A[22], b2, ac2, 0, 0, 0);
            ac3 = __builtin_amdgcn_mfma_f32_16x16x32_bf16(A[23], b3, ac3, 0, 0, 0);
        }
        asm volatile("s_waitcnt vmcnt(4)" ::: "memory");
        {
            bf16x8 b0 = *(const bf16x8*)(hwb + 8*512 + lane*8);
            bf16x8 b1 = *(const bf16x8*)(hwb + 9*512 + lane*8);
            bf16x8 b2 = *(const bf16x8*)(hwb + 10*512 + lane*8);
            bf16x8 b3 = *(const bf16x8*)(hwb + 11*512 + lane*8);
            ac0 = __builtin_amdgcn_mfma_f32_16x16x32_bf16(A[24], b0, ac0, 0, 0, 0);
            ac1 = __builtin_amdgcn_mfma_f32_16x16x32_bf16(A[25], b1, ac1, 0, 0, 0);
            ac2 = __builtin_amdgcn_mfma_f32_16x16x32_bf16(A[26], b2, ac2, 0, 0, 0);
            ac3 = __builtin_amdgcn_mfma_f32_16x16x32_bf16(A[27], b3, ac3, 0, 0, 0);
        }
        asm volatile("s_waitcnt vmcnt(0)" ::: "memory");
        {
            bf16x8 b0 = *(const bf16x8*)(hwb + 12*512 + lane*8);
            bf16x8 b1 = *(const bf16x8*)(hwb + 13*512 + lane*8);
            bf16x8 b2 = *(const bf16x8*)(hwb + 14*512 + lane*8);
            bf16x8 b3 = *(const bf16x8*)(hwb + 15*512 + lane*8);
            ac0 = __builtin_amdgcn_mfma_f32_16x16x32_bf16(A[28], b0, ac0, 0, 0, 0);
            ac1 = __builtin_amdgcn_mfma_f32_16x16x32_bf16(A[29], b1, ac1, 0, 0, 0);
            ac2 = __builtin_amdgcn_mfma_f32_16x16x32_bf16(A[30], b2, ac2, 0, 0, 0);
            ac3 = __builtin_amdgcn_mfma_f32_16x16x32_bf16(A[31], b3, ac3, 0, 0, 0);
        }

        f32x4 accT = (ac0 + ac1) + (ac2 + ac3);

        // ---- exchange gates (parity-buffered): one barrier, no WAR barrier
        const int p = t & 1;
        #pragma unroll
        for (int r = 0; r < 4; ++r)
            gl[p][wave][quad * 4 + r][l16] = accT[r];
        __syncthreads();   // gl[p] complete (no vmem outstanding -> drain free)

        const float vgi = gl[p][0][cu_u][cu_bl];
        const float vgf = gl[p][1][cu_u][cu_bl];
        const float vgg = gl[p][2][cu_u][cu_bl];
        const float vgo = gl[p][3][cu_u][cu_bl];

        // ---- gates -> c/h (one cell per thread)
        float ig = sigmoid_f(vgi + bias_i);
        float fg = sigmoid_f(vgf + bias_f);
        float gg = tanh_f(vgg + bias_g);
        float og = sigmoid_f(vgo + bias_o);
        float cn = fg * creg + ig * gg;
        creg = cn;
        float hn = og * tanh_f(cn);

        if (t == 0) {
            out[(size_t)batch * H_ + hu] = hn;                                    // row t=0
            out[(size_t)T_ * B_ * H_ + (size_t)batch * H_ + hu] = hn;             // h_f
            out[(size_t)T_ * B_ * H_ + B_ * H_ + (size_t)batch * H_ + hu] = cn;   // c_f
            break;
        }

        const unsigned tgt = (unsigned)(T_ - t);

        // ---- per-WAVE publish: gather own 4 batches via wave-private LDS
        hsc[wave][lane] = (__bf16)hn;        // [local batch lb=lane>>4][unit lane&15]
        asm volatile("s_waitcnt lgkmcnt(0)" ::: "memory");
        __builtin_amdgcn_sched_barrier(0);
        if (lane < 8) {
            const int lb = lane >> 1, qr = lane & 1;   // local batch, unit octet
            i32x4 hv = *(const i32x4*)(&hsc[wave][lb * 16 + qr * 8]);
            const int q = (wgM & 1) * 2 + qr;
            const int l16c = wave * 4 + lb;
            __bf16* dst = Hswz + (size_t)(t & 1) * 32768 +
                (size_t)(((wgM >> 1) * 4 + wgN) * 64 + q * 16 + l16c) * 8;
            asm volatile("global_store_dwordx4 %0, %1, off sc0 sc1"
                         :: "v"(dst), "v"(hv) : "memory");
        }
        // ---- release: ONLY the publish store is outstanding here
        asm volatile("s_waitcnt vmcnt(0)" ::: "memory");
        if (lane == 0) {
            const unsigned long long myf = (unsigned long long)(uintptr_t)
                (flags + wgN * 128 + wgM * 4 + wave);
            asm volatile("global_store_dword %0, %1, off sc0 sc1"
                         :: "v"(myf), "v"(tgt) : "memory");
        }

        // ---- deferred out store + next x-DMA (both drain inside the poll)
        out[(size_t)t * B_ * H_ + (size_t)batch * H_ + hu] = hn;
        ISSUE_X(t - 1);

        // ---- all-wave poll of this column's 128 per-wave flags; own wave's
        // flag masked true (our store may not be visible to ourselves yet)
        {
            const unsigned long long faddr = (unsigned long long)(uintptr_t)
                (flags + wgN * 128 + (lane & 31) * 4);
            i32x4 f4;
            asm volatile("global_load_dwordx4 %0, %1, off sc0 sc1\n\t"
                         "s_waitcnt vmcnt(0)"
                         : "=v"(f4) : "v"(faddr) : "memory");
            for (;;) {
                if ((lane & 31) == wgM) f4[wave] = (int)tgt;
                int m01 = f4[0] < f4[1] ? f4[0] : f4[1];
                int m23 = f4[2] < f4[3] ? f4[2] : f4[3];
                int m = m01 < m23 ? m01 : m23;
                if (__all(m >= (int)tgt)) break;
                asm volatile("global_load_dwordx4 %0, %1, off sc0 sc1\n\t"
                             "s_waitcnt vmcnt(0)"
                             : "=v"(f4) : "v"(faddr) : "memory");
            }
        }

        // ---- h-DMA for step t-1 (slab t&1): all producers' stores are
        // globally visible (their flags were), sc0sc1 loads see them.
        ISSUE_H(t & 1);
    }
    #undef ISSUE_X
    #undef ISSUE_H
}

extern "C" void kernel_launch(void* const* d_in, const int* in_sizes, int n_in,
                              void* d_out, int out_size, void* d_ws, size_t ws_size,
                              hipStream_t stream) {
    const float* input = (const float*)d_in[0];
    const float* h0   = (const float*)d_in[1];
    const float* c0   = (const float*)d_in[2];
    const float* W_ih = (const float*)d_in[3];
    const float* W_hh = (const float*)d_in[4];
    const float* b_ih = (const float*)d_in[5];
    const float* b_hh = (const float*)d_in[6];
    float* out = (float*)d_out;
    char* ws = (char*)d_ws;

    prep_w<<<(G_ * K_) / 256, 256, 0, stream>>>(W_ih, W_hh, b_ih, b_hh, ws);
    prep_x<<<(T_ * I_ * B_ / 8) / 256, 256, 0, stream>>>(input, ws);
    prep_h0<<<16, 256, 0, stream>>>(h0, ws);
    lstm_persist<<<NBLK, 256, 0, stream>>>(c0, out, ws);
}

// Round 3
// 1674.452 us; speedup vs baseline: 1.3195x; 1.3195x over previous
//
#include <hip/hip_runtime.h>
#include <math.h>
#include <stdint.h>

#define T_ 512
#define B_ 64
#define I_ 512
#define H_ 512
#define G_ 2048   // 4*H
#define K_ 1024   // I + H
#define NMR 32    // unit-group WGs (each owns 16 hidden units)
#define NCOL 4    // batch-column WGs (each owns 16 batches)
#define NBLK (NMR * NCOL)   // 128 persistent workgroups, 1 per CU

typedef __bf16 bf16x8 __attribute__((ext_vector_type(8)));
typedef float f32x4 __attribute__((ext_vector_type(4)));
typedef int i32x4 __attribute__((ext_vector_type(4)));

// Workspace layout (bytes):
//   W bf16 [G_][K_]     : 4 MB    ([W_ih | W_hh], bf16)
//   bias f32 [G_]       : 8 KB
//   hswz bf16 [2][64KB] : 128 KB  (h in MFMA B-frag layout, double-buffered)
//   flags u32 [4][64]   : 1 KB    (per-column, per-unit-group progress flags)
//   xswz bf16 [T][64KB] : 32 MB   (x in MFMA B-frag layout, read cached)
#define OFF_W    ((size_t)0)
#define OFF_BIAS (OFF_W + (size_t)G_ * K_ * 2)
#define OFF_HSWZ (OFF_BIAS + (size_t)G_ * 4)
#define OFF_BAR  (OFF_HSWZ + (size_t)2 * H_ * B_ * 2)
#define OFF_XSWZ (OFF_BAR + 1024)

// B-frag swizzle: frag-slot s = (kblk*4 + nblk)*64 + lane, holding 8 bf16:
//   quad = lane>>4, l16 = lane&15;  b = nblk*16 + l16;  k = kblk*32 + quad*8 + j

__global__ void prep_w(const float* __restrict__ W_ih, const float* __restrict__ W_hh,
                       const float* __restrict__ b_ih, const float* __restrict__ b_hh,
                       char* __restrict__ ws) {
    __bf16* W = (__bf16*)(ws + OFF_W);
    float* bias = (float*)(ws + OFF_BIAS);
    int idx = blockIdx.x * 256 + threadIdx.x;   // over G_*K_ = 2M
    int g = idx >> 10;
    int k = idx & (K_ - 1);
    float v = (k < I_) ? W_ih[g * I_ + k] : W_hh[g * H_ + (k - I_)];
    W[idx] = (__bf16)v;
    if (idx < G_) bias[idx] = b_ih[idx] + b_hh[idx];
    if (idx < 256) ((unsigned*)(ws + OFF_BAR))[idx] = 0u;
}

__global__ void prep_x(const float* __restrict__ input, char* __restrict__ ws) {
    __bf16* xswz = (__bf16*)(ws + OFF_XSWZ);
    int s = blockIdx.x * 256 + threadIdx.x;   // frag-chunk id
    int lane = s & 63;
    int nblk = (s >> 6) & 3;
    int kblk = (s >> 8) & 15;
    int t = s >> 12;
    int b = nblk * 16 + (lane & 15);
    int k = kblk * 32 + (lane >> 4) * 8;
    const float* src = input + ((size_t)t * B_ + b) * I_ + k;
    float4 v0 = *(const float4*)src;
    float4 v1 = *(const float4*)(src + 4);
    bf16x8 o;
    o[0]=(__bf16)v0.x; o[1]=(__bf16)v0.y; o[2]=(__bf16)v0.z; o[3]=(__bf16)v0.w;
    o[4]=(__bf16)v1.x; o[5]=(__bf16)v1.y; o[6]=(__bf16)v1.z; o[7]=(__bf16)v1.w;
    *(bf16x8*)(xswz + (size_t)s * 8) = o;
}

__global__ void prep_h0(const float* __restrict__ h0, char* __restrict__ ws) {
    __bf16* hswz0 = (__bf16*)(ws + OFF_HSWZ);   // parity 0: read by step t=511
    int s = blockIdx.x * 256 + threadIdx.x;     // 4096 slots
    int lane = s & 63;
    int nblk = (s >> 6) & 3;
    int hk = s >> 8;
    int b = nblk * 16 + (lane & 15);
    int u = hk * 32 + (lane >> 4) * 8;
    const float* src = h0 + (size_t)b * H_ + u;
    float4 v0 = *(const float4*)src;
    float4 v1 = *(const float4*)(src + 4);
    bf16x8 o;
    o[0]=(__bf16)v0.x; o[1]=(__bf16)v0.y; o[2]=(__bf16)v0.z; o[3]=(__bf16)v0.w;
    o[4]=(__bf16)v1.x; o[5]=(__bf16)v1.y; o[6]=(__bf16)v1.z; o[7]=(__bf16)v1.w;
    *(bf16x8*)(hswz0 + (size_t)s * 8) = o;
}

__device__ __forceinline__ float sigmoid_f(float x) { return 1.f / (1.f + __expf(-x)); }
__device__ __forceinline__ float tanh_f(float x) { return 1.f - 2.f / (1.f + __expf(2.f * x)); }

// Persistent reverse scan, 128 WGs x 256 threads (1/CU). WG (m,n) owns hidden
// units [m*16,m*16+16) x batches [n*16,n*16+16); wave = gate type, 4 accs.
// Protocol (role-split): wave0 publishes h + flag; wave1 polls the column's 32
// flags (own flag masked) -> publish-drain RT and poll RT overlap across waves.
// All waves drain vmcnt to 0 at loop bottom -> loop-top barriers are RAW
// s_barrier (no hidden drain); h-DMA issued after top barrier genuinely flies
// under the x-phase MFMAs (only vmcnt(0) waits are used anywhere, robust to
// compiler-inserted W reloads).
__launch_bounds__(256, 1)
__global__ void lstm_persist(const float* __restrict__ c0, float* out,
                             char* __restrict__ ws) {
    __shared__ __bf16 xbuf[8192];               // 16 x-frags x 512 elem (16 KB)
    __shared__ __bf16 hbuf[8192];               // 16 h-frags (16 KB)
    __shared__ float gl[4][16][17];             // [gate][unit][batch] exchange
    __shared__ __bf16 hstage[2][16][8];         // [lq][l16][j], 512 B

    const __bf16* W = (const __bf16*)(ws + OFF_W);
    const float* bias = (const float*)(ws + OFF_BIAS);
    __bf16* Hswz = (__bf16*)(ws + OFF_HSWZ);    // [2][32768 elements]
    const __bf16* Xswz = (const __bf16*)(ws + OFF_XSWZ);
    unsigned* flags = (unsigned*)(ws + OFF_BAR);

    const int tid = threadIdx.x;
    const int wave = tid >> 6;      // gate type
    const int lane = tid & 63;
    const int l16 = lane & 15;
    const int quad = lane >> 4;
    const int wgM = blockIdx.x & 31;    // unit group
    const int wgN = blockIdx.x >> 5;    // batch column

    // ---- A-fragments: ks 0..15 = W_ih cols, 16..31 = W_hh
    bf16x8 A[32];
    {
        const size_t arow = (size_t)(wave * H_ + wgM * 16 + l16) * K_ + quad * 8;
        #pragma unroll
        for (int ks = 0; ks < 32; ++ks)
            A[ks] = *(const bf16x8*)(W + arow + ks * 32);
    }

    // ---- cell state: thread owns (unit u = tid&15, batch bl = tid>>4)
    const int cu_u = tid & 15;
    const int cu_bl = tid >> 4;
    const int hu = wgM * 16 + cu_u;
    const int batch = wgN * 16 + cu_bl;
    float creg = c0[(size_t)batch * H_ + hu];
    const float bias_i = bias[hu];
    const float bias_f = bias[H_ + hu];
    const float bias_g = bias[2 * H_ + hu];
    const float bias_o = bias[3 * H_ + hu];

    #define ISSUE_X(tt) do {                                                          \
        const __bf16* xb_ = Xswz + (size_t)(tt) * 32768;                              \
        _Pragma("unroll")                                                             \
        for (int i_ = 0; i_ < 4; ++i_) {                                              \
            const int kb_ = wave * 4 + i_;                                            \
            __builtin_amdgcn_global_load_lds(                                         \
                (const __attribute__((address_space(1))) void*)(xb_ + (size_t)((kb_ * 4 + wgN) * 64 + lane) * 8), \
                (__attribute__((address_space(3))) void*)(xbuf + kb_ * 512),          \
                16, 0, 0);                                                            \
        }                                                                             \
    } while (0)

    // ---- prologue: x-DMA for t=511, drain everything -> all waves at vm=0
    ISSUE_X(T_ - 1);
    asm volatile("s_waitcnt vmcnt(0)" ::: "memory");
    __builtin_amdgcn_sched_barrier(0);

    for (int t = T_ - 1; ; --t) {
        // ---- loop-top: wave1 polls this column's 32 producers of h_{t+1}
        // (own flag masked: our data visibility is via our own drain+barrier).
        // All other waves arrive at the barrier with vmcnt already 0.
        if (t < T_ - 1 && wave == 1) {
            const unsigned target = (unsigned)(T_ - 1 - t);
            const unsigned long long faddr =
                (unsigned long long)(uintptr_t)(flags + wgN * 64 + (lane & 31));
            unsigned cur;
            do {
                asm volatile("global_load_dword %0, %1, off sc0 sc1\n\t"
                             "s_waitcnt vmcnt(0)"
                             : "=v"(cur) : "v"(faddr) : "memory");
            } while (!__all(lane >= 32 || lane == wgM || cur >= target));
        }
        __builtin_amdgcn_sched_barrier(0);
        __builtin_amdgcn_s_barrier();        // RAW: release, xbuf complete
        __builtin_amdgcn_sched_barrier(0);

        // ---- h-DMA (L2-bypassing): issued now, flies under the x-phase
        {
            const __bf16* hb = Hswz + (size_t)((t + 1) & 1) * 32768;
            #pragma unroll
            for (int i = 0; i < 4; ++i) {
                const int hk = wave * 4 + i;
                __builtin_amdgcn_global_load_lds(
                    (const __attribute__((address_space(1))) void*)(hb + (size_t)((hk * 4 + wgN) * 64 + lane) * 8),
                    (__attribute__((address_space(3))) void*)(hbuf + hk * 512),
                    16, 0, 0x11);
            }
        }

        // ---- x-phase: 16 MFMAs from xbuf, 4 accumulators (h-DMA in flight)
        f32x4 ac0 = {0,0,0,0}, ac1 = {0,0,0,0}, ac2 = {0,0,0,0}, ac3 = {0,0,0,0};
        #pragma unroll
        for (int f = 0; f < 4; ++f) {
            bf16x8 b0 = *(const bf16x8*)(xbuf + (4*f+0) * 512 + lane * 8);
            bf16x8 b1 = *(const bf16x8*)(xbuf + (4*f+1) * 512 + lane * 8);
            bf16x8 b2 = *(const bf16x8*)(xbuf + (4*f+2) * 512 + lane * 8);
            bf16x8 b3 = *(const bf16x8*)(xbuf + (4*f+3) * 512 + lane * 8);
            ac0 = __builtin_amdgcn_mfma_f32_16x16x32_bf16(A[4*f+0], b0, ac0, 0, 0, 0);
            ac1 = __builtin_amdgcn_mfma_f32_16x16x32_bf16(A[4*f+1], b1, ac1, 0, 0, 0);
            ac2 = __builtin_amdgcn_mfma_f32_16x16x32_bf16(A[4*f+2], b2, ac2, 0, 0, 0);
            ac3 = __builtin_amdgcn_mfma_f32_16x16x32_bf16(A[4*f+3], b3, ac3, 0, 0, 0);
        }

        // ---- own h-DMA landed; all-wave rendezvous -> hbuf complete
        asm volatile("s_waitcnt vmcnt(0)" ::: "memory");
        __builtin_amdgcn_sched_barrier(0);
        __builtin_amdgcn_s_barrier();
        __builtin_amdgcn_sched_barrier(0);

        // ---- h-phase: 16 MFMAs from hbuf
        #pragma unroll
        for (int f = 0; f < 4; ++f) {
            bf16x8 b0 = *(const bf16x8*)(hbuf + (4*f+0) * 512 + lane * 8);
            bf16x8 b1 = *(const bf16x8*)(hbuf + (4*f+1) * 512 + lane * 8);
            bf16x8 b2 = *(const bf16x8*)(hbuf + (4*f+2) * 512 + lane * 8);
            bf16x8 b3 = *(const bf16x8*)(hbuf + (4*f+3) * 512 + lane * 8);
            ac0 = __builtin_amdgcn_mfma_f32_16x16x32_bf16(A[16+4*f+0], b0, ac0, 0, 0, 0);
            ac1 = __builtin_amdgcn_mfma_f32_16x16x32_bf16(A[16+4*f+1], b1, ac1, 0, 0, 0);
            ac2 = __builtin_amdgcn_mfma_f32_16x16x32_bf16(A[16+4*f+2], b2, ac2, 0, 0, 0);
            ac3 = __builtin_amdgcn_mfma_f32_16x16x32_bf16(A[16+4*f+3], b3, ac3, 0, 0, 0);
        }
        f32x4 accT = (ac0 + ac1) + (ac2 + ac3);

        // ---- exchange gates: col(batch) = lane&15, row(unit) = quad*4 + reg
        #pragma unroll
        for (int r = 0; r < 4; ++r)
            gl[wave][quad * 4 + r][l16] = accT[r];
        __syncthreads();                         // drain-free: vmcnt already 0

        // ---- gates -> c/h (one cell per thread); stage hn for publish
        float ig = sigmoid_f(gl[0][cu_u][cu_bl] + bias_i);
        float fg = sigmoid_f(gl[1][cu_u][cu_bl] + bias_f);
        float gg = tanh_f(gl[2][cu_u][cu_bl] + bias_g);
        float og = sigmoid_f(gl[3][cu_u][cu_bl] + bias_o);
        float cn = fg * creg + ig * gg;
        creg = cn;
        float hn = og * tanh_f(cn);
        hstage[cu_u >> 3][cu_bl][cu_u & 7] = (__bf16)hn;
        __syncthreads();                         // hstage complete (drain-free)

        // ---- bottom: issue out + next-x FIRST, then publish; ONE vmcnt(0)
        // covers all (overlapped completions), then flag. Every wave leaves
        // the bottom with vmcnt == 0.
        out[(size_t)t * B_ * H_ + (size_t)batch * H_ + hu] = hn;
        if (t == 0) {
            out[(size_t)T_ * B_ * H_ + (size_t)batch * H_ + hu] = hn;             // h_f
            out[(size_t)T_ * B_ * H_ + B_ * H_ + (size_t)batch * H_ + hu] = cn;   // c_f
            break;
        }
        ISSUE_X(t - 1);
        if (tid < 32) {
            i32x4 v = *(i32x4*)((__bf16*)hstage + tid * 8);
            const int lqc = tid >> 4, l16c = tid & 15;
            const int hk = wgM >> 1, q0 = (wgM & 1) * 2;
            size_t off = (size_t)((hk * 4 + wgN) * 64 + (q0 + lqc) * 16 + l16c) * 8;
            __bf16* dst = Hswz + (size_t)(t & 1) * 32768 + off;
            asm volatile("global_store_dwordx4 %0, %1, off sc0 sc1"
                         :: "v"(dst), "v"(v) : "memory");
        }
        asm volatile("s_waitcnt vmcnt(0)" ::: "memory");   // out+x+publish drained
        if (tid == 0) {   // same wave as publishers -> ordered by the drain
            const unsigned val = (unsigned)(T_ - t);
            const unsigned long long faddr =
                (unsigned long long)(uintptr_t)(flags + wgN * 64 + wgM);
            asm volatile("global_store_dword %0, %1, off sc0 sc1"
                         :: "v"(faddr), "v"(val) : "memory");
        }
    }
    #undef ISSUE_X
}

extern "C" void kernel_launch(void* const* d_in, const int* in_sizes, int n_in,
                              void* d_out, int out_size, void* d_ws, size_t ws_size,
                              hipStream_t stream) {
    const float* input = (const float*)d_in[0];
    const float* h0   = (const float*)d_in[1];
    const float* c0   = (const float*)d_in[2];
    const float* W_ih = (const float*)d_in[3];
    const float* W_hh = (const float*)d_in[4];
    const float* b_ih = (const float*)d_in[5];
    const float* b_hh = (const float*)d_in[6];
    float* out = (float*)d_out;
    char* ws = (char*)d_ws;

    prep_w<<<(G_ * K_) / 256, 256, 0, stream>>>(W_ih, W_hh, b_ih, b_hh, ws);
    prep_x<<<(T_ * I_ * B_ / 8) / 256, 256, 0, stream>>>(input, ws);
    prep_h0<<<16, 256, 0, stream>>>(h0, ws);
    lstm_persist<<<NBLK, 256, 0, stream>>>(c0, out, ws);
}

// Round 5
// 1565.634 us; speedup vs baseline: 1.4113x; 1.0695x over previous
//
#include <hip/hip_runtime.h>
#include <math.h>
#include <stdint.h>

#define T_ 512
#define B_ 64
#define I_ 512
#define H_ 512
#define G_ 2048   // 4*H
#define K_ 1024   // I + H
#define NMR 32    // unit-group WGs (each owns 16 hidden units)
#define NCOL 4    // batch-column WGs (each owns 16 batches)
#define NBLK (NMR * NCOL)   // 128 persistent workgroups, 1 per CU

typedef __bf16 bf16x8 __attribute__((ext_vector_type(8)));
typedef float f32x4 __attribute__((ext_vector_type(4)));
typedef int i32x4 __attribute__((ext_vector_type(4)));

// Workspace layout (bytes):
//   W bf16 [G_][K_]     : 4 MB    ([W_ih | W_hh], bf16)
//   bias f32 [G_]       : 8 KB
//   hswz bf16 [2][64KB] : 128 KB  (h in MFMA B-frag layout, double-buffered)
//   flags u32 [4][64]   : 1 KB    (per-column, per-unit-group progress flags)
//   xswz bf16 [T][64KB] : 32 MB   (x in MFMA B-frag layout, read cached)
#define OFF_W    ((size_t)0)
#define OFF_BIAS (OFF_W + (size_t)G_ * K_ * 2)
#define OFF_HSWZ (OFF_BIAS + (size_t)G_ * 4)
#define OFF_BAR  (OFF_HSWZ + (size_t)2 * H_ * B_ * 2)
#define OFF_XSWZ (OFF_BAR + 1024)

// B-frag swizzle: frag-slot s = (kblk*4 + nblk)*64 + lane, holding 8 bf16:
//   quad = lane>>4, l16 = lane&15;  b = nblk*16 + l16;  k = kblk*32 + quad*8 + j

__global__ void prep_w(const float* __restrict__ W_ih, const float* __restrict__ W_hh,
                       const float* __restrict__ b_ih, const float* __restrict__ b_hh,
                       char* __restrict__ ws) {
    __bf16* W = (__bf16*)(ws + OFF_W);
    float* bias = (float*)(ws + OFF_BIAS);
    int idx = blockIdx.x * 256 + threadIdx.x;   // over G_*K_ = 2M
    int g = idx >> 10;
    int k = idx & (K_ - 1);
    float v = (k < I_) ? W_ih[g * I_ + k] : W_hh[g * H_ + (k - I_)];
    W[idx] = (__bf16)v;
    if (idx < G_) bias[idx] = b_ih[idx] + b_hh[idx];
    if (idx < 256) ((unsigned*)(ws + OFF_BAR))[idx] = 0u;
}

__global__ void prep_x(const float* __restrict__ input, char* __restrict__ ws) {
    __bf16* xswz = (__bf16*)(ws + OFF_XSWZ);
    int s = blockIdx.x * 256 + threadIdx.x;   // frag-chunk id
    int lane = s & 63;
    int nblk = (s >> 6) & 3;
    int kblk = (s >> 8) & 15;
    int t = s >> 12;
    int b = nblk * 16 + (lane & 15);
    int k = kblk * 32 + (lane >> 4) * 8;
    const float* src = input + ((size_t)t * B_ + b) * I_ + k;
    float4 v0 = *(const float4*)src;
    float4 v1 = *(const float4*)(src + 4);
    bf16x8 o;
    o[0]=(__bf16)v0.x; o[1]=(__bf16)v0.y; o[2]=(__bf16)v0.z; o[3]=(__bf16)v0.w;
    o[4]=(__bf16)v1.x; o[5]=(__bf16)v1.y; o[6]=(__bf16)v1.z; o[7]=(__bf16)v1.w;
    *(bf16x8*)(xswz + (size_t)s * 8) = o;
}

__global__ void prep_h0(const float* __restrict__ h0, char* __restrict__ ws) {
    __bf16* hswz0 = (__bf16*)(ws + OFF_HSWZ);   // parity 0: read by step t=511
    int s = blockIdx.x * 256 + threadIdx.x;     // 4096 slots
    int lane = s & 63;
    int nblk = (s >> 6) & 3;
    int hk = s >> 8;
    int b = nblk * 16 + (lane & 15);
    int u = hk * 32 + (lane >> 4) * 8;
    const float* src = h0 + (size_t)b * H_ + u;
    float4 v0 = *(const float4*)src;
    float4 v1 = *(const float4*)(src + 4);
    bf16x8 o;
    o[0]=(__bf16)v0.x; o[1]=(__bf16)v0.y; o[2]=(__bf16)v0.z; o[3]=(__bf16)v0.w;
    o[4]=(__bf16)v1.x; o[5]=(__bf16)v1.y; o[6]=(__bf16)v1.z; o[7]=(__bf16)v1.w;
    *(bf16x8*)(hswz0 + (size_t)s * 8) = o;
}

__device__ __forceinline__ float sigmoid_f(float x) { return 1.f / (1.f + __expf(-x)); }
__device__ __forceinline__ float tanh_f(float x) { return 1.f - 2.f / (1.f + __expf(2.f * x)); }

// Persistent reverse scan, 128 WGs x 256 threads (1/CU). WG (m,n) owns hidden
// units [m*16,m*16+16) x batches [n*16,n*16+16); wave = gate type, 4 accs.
// Role-split bottom (three RTs in three different waves, overlapped):
//   wave0: publish h-block -> vmcnt(0) [publish ONLY] -> flag   (~1 RT)
//   wave1: nothing at bottom; polls 32 flags at top (clean samples)
//   waves2/3: x-prefetch (8 frags each) -> vmcnt(0)             (~1 RT)
// out-stores are deferred past the next top barrier and drain inside the
// mid-step vmcnt(0) that already waits for h-DMA. A[] is pinned in VGPRs via
// per-iteration keep-alive asm (no W reloads in the MFMA phases). Only
// vmcnt(0) waits are used (robust to compiler-inserted vmem).
__launch_bounds__(256, 1)
__global__ void lstm_persist(const float* __restrict__ c0, float* out,
                             char* __restrict__ ws) {
    __shared__ __bf16 xbuf[8192];               // 16 x-frags x 512 elem (16 KB)
    __shared__ __bf16 hbuf[8192];               // 16 h-frags (16 KB)
    __shared__ float gl[4][16][17];             // [gate][unit][batch] exchange
    __shared__ __bf16 hstage[2][16][8];         // [lq][l16][j], 512 B

    const __bf16* W = (const __bf16*)(ws + OFF_W);
    const float* bias = (const float*)(ws + OFF_BIAS);
    __bf16* Hswz = (__bf16*)(ws + OFF_HSWZ);    // [2][32768 elements]
    const __bf16* Xswz = (const __bf16*)(ws + OFF_XSWZ);
    unsigned* flags = (unsigned*)(ws + OFF_BAR);

    const int tid = threadIdx.x;
    const int wave = tid >> 6;      // gate type
    const int lane = tid & 63;
    const int l16 = lane & 15;
    const int quad = lane >> 4;
    const int wgM = blockIdx.x & 31;    // unit group
    const int wgN = blockIdx.x >> 5;    // batch column

    // ---- A-fragments: ks 0..15 = W_ih cols, 16..31 = W_hh (128 VGPRs)
    bf16x8 A[32];
    {
        const size_t arow = (size_t)(wave * H_ + wgM * 16 + l16) * K_ + quad * 8;
        #pragma unroll
        for (int ks = 0; ks < 32; ++ks)
            A[ks] = *(const bf16x8*)(W + arow + ks * 32);
    }
    #pragma unroll
    for (int ks = 0; ks < 32; ++ks) asm volatile("" : "+v"(A[ks]));

    // ---- cell state: thread owns (unit u = tid&15, batch bl = tid>>4)
    const int cu_u = tid & 15;
    const int cu_bl = tid >> 4;
    const int hu = wgM * 16 + cu_u;
    const int batch = wgN * 16 + cu_bl;
    float creg = c0[(size_t)batch * H_ + hu];
    const float bias_i = bias[hu];
    const float bias_f = bias[H_ + hu];
    const float bias_g = bias[2 * H_ + hu];
    const float bias_o = bias[3 * H_ + hu];
    float hn = 0.f;

    // ---- prologue: x-prefetch for t=511 by waves 2/3; all drain to vm=0
    if (wave >= 2) {
        const __bf16* xb = Xswz + (size_t)(T_ - 1) * 32768;
        #pragma unroll
        for (int i = 0; i < 8; ++i) {
            const int kb = (wave - 2) * 8 + i;
            __builtin_amdgcn_global_load_lds(
                (const __attribute__((address_space(1))) void*)(xb + (size_t)((kb * 4 + wgN) * 64 + lane) * 8),
                (__attribute__((address_space(3))) void*)(xbuf + kb * 512),
                16, 0, 0);
        }
    }
    asm volatile("s_waitcnt vmcnt(0)" ::: "memory");
    __builtin_amdgcn_sched_barrier(0);

    for (int t = T_ - 1; ; --t) {
        // ---- loop-top: wave1 polls this column's 32 producers of h_{t+1}
        // (own flag masked). Its samples wait only on their own flag load.
        if (t < T_ - 1 && wave == 1) {
            const unsigned target = (unsigned)(T_ - 1 - t);
            const unsigned long long faddr =
                (unsigned long long)(uintptr_t)(flags + wgN * 64 + (lane & 31));
            unsigned cur;
            do {
                asm volatile("global_load_dword %0, %1, off sc0 sc1\n\t"
                             "s_waitcnt vmcnt(0)"
                             : "=v"(cur) : "v"(faddr) : "memory");
            } while (!__all(lane >= 32 || lane == wgM || cur >= target));
        }
        __builtin_amdgcn_sched_barrier(0);
        __builtin_amdgcn_s_barrier();        // RAW: release; xbuf complete
        __builtin_amdgcn_sched_barrier(0);

        // ---- keep A resident across the loop body
        #pragma unroll
        for (int ks = 0; ks < 32; ++ks) asm volatile("" : "+v"(A[ks]));

        // ---- deferred out-store for step t+1 (drains at the mid vmcnt(0))
        if (t != T_ - 1)
            out[(size_t)(t + 1) * B_ * H_ + (size_t)batch * H_ + hu] = hn;

        // ---- h-DMA (L2-bypassing): issued now, flies under the x-phase
        {
            const __bf16* hb = Hswz + (size_t)((t + 1) & 1) * 32768;
            #pragma unroll
            for (int i = 0; i < 4; ++i) {
                const int hk = wave * 4 + i;
                __builtin_amdgcn_global_load_lds(
                    (const __attribute__((address_space(1))) void*)(hb + (size_t)((hk * 4 + wgN) * 64 + lane) * 8),
                    (__attribute__((address_space(3))) void*)(hbuf + hk * 512),
                    16, 0, 0x11);
            }
        }

        // ---- x-phase: 16 MFMAs from xbuf, 4 accumulators (h-DMA in flight)
        f32x4 ac0 = {0,0,0,0}, ac1 = {0,0,0,0}, ac2 = {0,0,0,0}, ac3 = {0,0,0,0};
        #pragma unroll
        for (int f = 0; f < 4; ++f) {
            bf16x8 b0 = *(const bf16x8*)(xbuf + (4*f+0) * 512 + lane * 8);
            bf16x8 b1 = *(const bf16x8*)(xbuf + (4*f+1) * 512 + lane * 8);
            bf16x8 b2 = *(const bf16x8*)(xbuf + (4*f+2) * 512 + lane * 8);
            bf16x8 b3 = *(const bf16x8*)(xbuf + (4*f+3) * 512 + lane * 8);
            ac0 = __builtin_amdgcn_mfma_f32_16x16x32_bf16(A[4*f+0], b0, ac0, 0, 0, 0);
            ac1 = __builtin_amdgcn_mfma_f32_16x16x32_bf16(A[4*f+1], b1, ac1, 0, 0, 0);
            ac2 = __builtin_amdgcn_mfma_f32_16x16x32_bf16(A[4*f+2], b2, ac2, 0, 0, 0);
            ac3 = __builtin_amdgcn_mfma_f32_16x16x32_bf16(A[4*f+3], b3, ac3, 0, 0, 0);
        }

        // ---- own h-DMA (+ deferred out) landed; rendezvous -> hbuf complete
        asm volatile("s_waitcnt vmcnt(0)" ::: "memory");
        __builtin_amdgcn_sched_barrier(0);
        __builtin_amdgcn_s_barrier();
        __builtin_amdgcn_sched_barrier(0);

        // ---- h-phase: 16 MFMAs from hbuf
        #pragma unroll
        for (int f = 0; f < 4; ++f) {
            bf16x8 b0 = *(const bf16x8*)(hbuf + (4*f+0) * 512 + lane * 8);
            bf16x8 b1 = *(const bf16x8*)(hbuf + (4*f+1) * 512 + lane * 8);
            bf16x8 b2 = *(const bf16x8*)(hbuf + (4*f+2) * 512 + lane * 8);
            bf16x8 b3 = *(const bf16x8*)(hbuf + (4*f+3) * 512 + lane * 8);
            ac0 = __builtin_amdgcn_mfma_f32_16x16x32_bf16(A[16+4*f+0], b0, ac0, 0, 0, 0);
            ac1 = __builtin_amdgcn_mfma_f32_16x16x32_bf16(A[16+4*f+1], b1, ac1, 0, 0, 0);
            ac2 = __builtin_amdgcn_mfma_f32_16x16x32_bf16(A[16+4*f+2], b2, ac2, 0, 0, 0);
            ac3 = __builtin_amdgcn_mfma_f32_16x16x32_bf16(A[16+4*f+3], b3, ac3, 0, 0, 0);
        }
        f32x4 accT = (ac0 + ac1) + (ac2 + ac3);

        // ---- exchange gates: col(batch) = lane&15, row(unit) = quad*4 + reg
        #pragma unroll
        for (int r = 0; r < 4; ++r)
            gl[wave][quad * 4 + r][l16] = accT[r];
        __syncthreads();                         // drain-free: vmcnt already 0

        // ---- gates -> c/h (one cell per thread); stage hn for publish
        float ig = sigmoid_f(gl[0][cu_u][cu_bl] + bias_i);
        float fg = sigmoid_f(gl[1][cu_u][cu_bl] + bias_f);
        float gg = tanh_f(gl[2][cu_u][cu_bl] + bias_g);
        float og = sigmoid_f(gl[3][cu_u][cu_bl] + bias_o);
        float cn = fg * creg + ig * gg;
        creg = cn;
        hn = og * tanh_f(cn);
        hstage[cu_u >> 3][cu_bl][cu_u & 7] = (__bf16)hn;
        __syncthreads();                         // hstage complete (drain-free)

        if (t == 0) {
            out[(size_t)batch * H_ + hu] = hn;                                    // row 0
            out[(size_t)T_ * B_ * H_ + (size_t)batch * H_ + hu] = hn;             // h_f
            out[(size_t)T_ * B_ * H_ + B_ * H_ + (size_t)batch * H_ + hu] = cn;   // c_f
            break;
        }

        // ---- bottom, role-split (per-wave drains overlap across waves)
        if (wave == 0) {
            // publish h_t frags, drain publish ONLY, then release flag
            if (lane < 32) {
                i32x4 v = *(i32x4*)((__bf16*)hstage + lane * 8);
                const int lqc = lane >> 4, l16c = lane & 15;
                const int hk = wgM >> 1, q0 = (wgM & 1) * 2;
                size_t off = (size_t)((hk * 4 + wgN) * 64 + (q0 + lqc) * 16 + l16c) * 8;
                __bf16* dst = Hswz + (size_t)(t & 1) * 32768 + off;
                asm volatile("global_store_dwordx4 %0, %1, off sc0 sc1"
                             :: "v"(dst), "v"(v) : "memory");
            }
            asm volatile("s_waitcnt vmcnt(0)" ::: "memory");
            if (lane == 0) {
                const unsigned val = (unsigned)(T_ - t);
                const unsigned long long faddr =
                    (unsigned long long)(uintptr_t)(flags + wgN * 64 + wgM);
                asm volatile("global_store_dword %0, %1, off sc0 sc1"
                             :: "v"(faddr), "v"(val) : "memory");
            }
        } else if (wave >= 2) {
            // x-prefetch for t-1 (8 frags each), drained before the top barrier
            const __bf16* xb = Xswz + (size_t)(t - 1) * 32768;
            #pragma unroll
            for (int i = 0; i < 8; ++i) {
                const int kb = (wave - 2) * 8 + i;
                __builtin_amdgcn_global_load_lds(
                    (const __attribute__((address_space(1))) void*)(xb + (size_t)((kb * 4 + wgN) * 64 + lane) * 8),
                    (__attribute__((address_space(3))) void*)(xbuf + kb * 512),
                    16, 0, 0);
            }
            asm volatile("s_waitcnt vmcnt(0)" ::: "memory");
        }
        // wave1: nothing outstanding; proceeds straight to the poll
    }
}

extern "C" void kernel_launch(void* const* d_in, const int* in_sizes, int n_in,
                              void* d_out, int out_size, void* d_ws, size_t ws_size,
                              hipStream_t stream) {
    const float* input = (const float*)d_in[0];
    const float* h0   = (const float*)d_in[1];
    const float* c0   = (const float*)d_in[2];
    const float* W_ih = (const float*)d_in[3];
    const float* W_hh = (const float*)d_in[4];
    const float* b_ih = (const float*)d_in[5];
    const float* b_hh = (const float*)d_in[6];
    float* out = (float*)d_out;
    char* ws = (char*)d_ws;

    prep_w<<<(G_ * K_) / 256, 256, 0, stream>>>(W_ih, W_hh, b_ih, b_hh, ws);
    prep_x<<<(T_ * I_ * B_ / 8) / 256, 256, 0, stream>>>(input, ws);
    prep_h0<<<16, 256, 0, stream>>>(h0, ws);
    lstm_persist<<<NBLK, 256, 0, stream>>>(c0, out, ws);
}